// Round 9
// baseline (398.773 us; speedup 1.0000x reference)
//
#include <hip/hip_runtime.h>
#include <hip/hip_bf16.h>

using f32x4 = __attribute__((ext_vector_type(4))) float;
using s16x8 = __attribute__((ext_vector_type(8))) short;
using i32x4 = __attribute__((ext_vector_type(4))) int;

#define NTOT 16384
#define NUSER 8192
#define DIM 256

__device__ __forceinline__ unsigned short f2bf(float f) {
  union { float f; unsigned u; } v; v.f = f;
  unsigned r = v.u + 0x7FFFu + ((v.u >> 16) & 1u);   // RNE
  return (unsigned short)(r >> 16);
}

__device__ __forceinline__ unsigned pack2bf(float x, float y) {
  float2 t; t.x = x; t.y = y;
  __hip_bfloat162 h = __float22bfloat162_rn(t);
  union { __hip_bfloat162 h; unsigned u; } cv; cv.h = h;
  return cv.u;
}

__device__ __forceinline__ void gload_lds16(const void* g, void* l) {
  __builtin_amdgcn_global_load_lds(
      (const __attribute__((address_space(1))) unsigned int*)g,
      (__attribute__((address_space(3))) unsigned int*)l, 16, 0, 0);
}

// ---------------- transpose + f32->bf16: dst[N][K] = src[K][N] ----------------
__global__ __launch_bounds__(256) void transpose_cvt(const float* __restrict__ src,
                                                     unsigned short* __restrict__ dst,
                                                     int K, int N) {
  __shared__ float tile[64][65];
  const int k0 = blockIdx.x * 64, n0 = blockIdx.y * 64;
  const int t = threadIdx.x;
#pragma unroll
  for (int i = 0; i < 16; i++) {
    int idx = i * 256 + t, r = idx >> 6, c = idx & 63;
    tile[r][c] = src[(size_t)(k0 + r) * N + n0 + c];
  }
  __syncthreads();
#pragma unroll
  for (int i = 0; i < 16; i++) {
    int idx = i * 256 + t, r = idx >> 6, c = idx & 63;
    dst[(size_t)(n0 + r) * K + k0 + c] = f2bf(tile[c][r]);
  }
}

// 5 square 256x256 weights in one launch
__global__ __launch_bounds__(256) void transpose_w5(const float* __restrict__ w0,
                                                    const float* __restrict__ w1,
                                                    const float* __restrict__ w2,
                                                    const float* __restrict__ w3,
                                                    const float* __restrict__ w4,
                                                    unsigned short* __restrict__ dstbase) {
  __shared__ float tile[64][65];
  const float* srcs[5] = {w0, w1, w2, w3, w4};
  const float* src = srcs[blockIdx.z];
  unsigned short* dst = dstbase + (size_t)blockIdx.z * 65536;
  const int k0 = blockIdx.x * 64, n0 = blockIdx.y * 64;
  const int t = threadIdx.x;
#pragma unroll
  for (int i = 0; i < 16; i++) {
    int idx = i * 256 + t, r = idx >> 6, c = idx & 63;
    tile[r][c] = src[(size_t)(k0 + r) * 256 + n0 + c];
  }
  __syncthreads();
#pragma unroll
  for (int i = 0; i < 16; i++) {
    int idx = i * 256 + t, r = idx >> 6, c = idx & 63;
    dst[(size_t)(n0 + r) * 256 + k0 + c] = f2bf(tile[c][r]);
  }
}

// ---------------- gemm1 v9: F1p[s] = A[:, sK:] @ feat[sK:, :] ----------------
// BM=64, BN=256, BK=64, split-K=2, grid 512, LDS 80 KB -> 2 blocks/CU.
// XCD remap keeps each XCD's 4 MiB Ft slice L2-resident. Counted-vmcnt
// 2-buffer schedule: B issue-distance 1 (into barrier-separated buffer),
// A issue-distance 2 (reg dbuf), barriers at vmcnt(2), never 0 until tail.
struct APair { f32x4 a, b; };

__global__ __launch_bounds__(512, 4) void gemm1(const float* __restrict__ A,
                                                const unsigned short* __restrict__ Ft,
                                                float* __restrict__ F1p) {
  __shared__ char smem[80 * 1024];
  char* const Ab0 = smem;                 // [64][64] bf16, 8 KB each
  char* const Ab1 = smem + 8 * 1024;
  char* const Bb0 = smem + 16 * 1024;     // [256][64] bf16, 32 KB each
  char* const Bb1 = smem + 48 * 1024;

  const int tid = threadIdx.x;
  const int l = tid & 63, w = tid >> 6;
  const int wm = w >> 2, wn = w & 3;      // 2x4 waves, wave tile 32x64
  const int lr = l & 15, lk = l >> 4;

  const int lin = blockIdx.x;             // 0..511
  const int xcd = lin & 7, slot = lin >> 3;   // slot 0..63
  const int ks = xcd >> 2;                // 0..1
  const int mblk = (xcd & 3) * 64 + slot; // 0..255
  const int m0 = mblk * 64;
  const size_t ks0 = (size_t)ks * 8192;
  float* out = F1p + (size_t)ks * NTOT * DIM;

  // A staging: 64 rows x 64 f32; thread: row=tid>>3, 8 f32 at col (tid&7)*8
  const int ar = tid >> 3, ac = tid & 7;
  const float* asrc = A + (size_t)(m0 + ar) * NTOT + ks0 + ac * 8;
  const int aoff = ar * 128 + ((ac * 16) ^ ((ar & 7) << 4));

  // B staging via global_load_lds: per wave 4 x 1KB (rows w*32..w*32+31)
  const int brin = l >> 3;
  const int bldso = w * 4096;
  const char* bsrc = (const char*)Ft + (size_t)(w * 32 + brin) * (NTOT * 2) +
                     ks0 * 2 + (((l & 7) * 16) ^ (brin << 4));

  f32x4 zero = {0.f, 0.f, 0.f, 0.f};
  f32x4 acc[2][4];
#pragma unroll
  for (int i = 0; i < 2; i++)
#pragma unroll
    for (int j = 0; j < 4; j++) acc[i][j] = zero;

  APair avP, avQ;   // avP: even steps, avQ: odd steps

  auto issueB = [&](int t, char* Bb) {
#pragma unroll
    for (int i = 0; i < 4; i++)
      gload_lds16(bsrc + (size_t)i * 8 * (NTOT * 2) + t * 128,
                  Bb + bldso + i * 1024);
  };
  auto loadA = [&](int t, APair& s) {
    s.a = __builtin_nontemporal_load((const f32x4*)(asrc + t * 64));
    s.b = __builtin_nontemporal_load((const f32x4*)(asrc + t * 64 + 4));
  };
  auto writeA = [&](const APair& s, char* Ab) {
    i32x4 p;
    p.x = (int)pack2bf(s.a.x, s.a.y);
    p.y = (int)pack2bf(s.a.z, s.a.w);
    p.z = (int)pack2bf(s.b.x, s.b.y);
    p.w = (int)pack2bf(s.b.z, s.b.w);
    *(i32x4*)(Ab + aoff) = p;
  };
  auto compute = [&](const char* Ab, const char* Bb) {
#pragma unroll
    for (int kh = 0; kh < 2; kh++) {
      s16x8 af[2], bf[4];
#pragma unroll
      for (int mt = 0; mt < 2; mt++) {
        int r = wm * 32 + mt * 16 + lr;
        int off = r * 128 + ((kh * 64 + lk * 16) ^ ((r & 7) << 4));
        af[mt] = *(const s16x8*)(Ab + off);
      }
#pragma unroll
      for (int nt = 0; nt < 4; nt++) {
        int n = wn * 64 + nt * 16 + lr;
        int off = n * 128 + ((kh * 64 + lk * 16) ^ ((n & 7) << 4));
        bf[nt] = *(const s16x8*)(Bb + off);
      }
#pragma unroll
      for (int mt = 0; mt < 2; mt++)
#pragma unroll
        for (int nt = 0; nt < 4; nt++)
          acc[mt][nt] = __builtin_amdgcn_mfma_f32_16x16x32_bf16(af[mt], bf[nt],
                                                                acc[mt][nt], 0, 0, 0);
    }
  };

#define BAR_V(N)                                                   \
  asm volatile("s_waitcnt vmcnt(" #N ") lgkmcnt(0)" ::: "memory"); \
  __builtin_amdgcn_s_barrier();                                    \
  __builtin_amdgcn_sched_barrier(0);

  // prologue: B(0)->Bb0 drained; A(0)->Ab0 written; A(1) in flight
  issueB(0, Bb0);
  loadA(0, avP);
  writeA(avP, Ab0);          // implicit wait drains A(0) (and B(0))
  loadA(1, avQ);
  BAR_V(2)                   // keep A(1) in flight

  // phases t = 0..123
  for (int t = 0; t < 124; t += 2) {
    // even phase t: compute step t from (Ab0,Bb0)
    issueB(t + 1, Bb1);               // Bb1 last read phase t-1: safe
    loadA(t + 2, avP);
    compute(Ab0, Bb0);
    writeA(avQ, Ab1);                 // A(t+1) -> Ab1 (last read t-1)
    BAR_V(2)                          // drain B(t+1); keep A(t+2)
    // odd phase t+1
    issueB(t + 2, Bb0);
    loadA(t + 3, avQ);
    compute(Ab1, Bb1);
    writeA(avP, Ab0);                 // A(t+2) -> Ab0
    BAR_V(2)
  }
  // phase 124
  issueB(125, Bb1);
  loadA(126, avP);
  compute(Ab0, Bb0);
  writeA(avQ, Ab1);
  BAR_V(2)
  // phase 125
  issueB(126, Bb0);
  loadA(127, avQ);
  compute(Ab1, Bb1);
  writeA(avP, Ab0);
  BAR_V(2)
  // phase 126 (no more A issues)
  issueB(127, Bb1);
  compute(Ab0, Bb0);
  writeA(avQ, Ab1);
  BAR_V(0)
  // phase 127
  compute(Ab1, Bb1);
#undef BAR_V

#pragma unroll
  for (int mt = 0; mt < 2; mt++) {
    int rbase = m0 + wm * 32 + mt * 16 + lk * 4;
#pragma unroll
    for (int nt = 0; nt < 4; nt++) {
      int c = wn * 64 + nt * 16 + lr;
#pragma unroll
      for (int j = 0; j < 4; j++)
        __builtin_nontemporal_store(acc[mt][nt][j],
                                    out + (size_t)(rbase + j) * DIM + c);
    }
  }
}

// ---------------- stage2: x = relu((P0+P1) @ WgT^T + bg) -> bf16 ----------------
__global__ __launch_bounds__(512) void mlp_in(const float* __restrict__ P,
                                              const unsigned short* __restrict__ WT,
                                              const float* __restrict__ bias,
                                              unsigned short* __restrict__ out) {
  __shared__ char smem[40 * 1024];
  char* Ab = smem;             // [64][64] bf16 8KB
  char* Bb = smem + 8 * 1024;  // [256][64] bf16 32KB
  const int tid = threadIdx.x, l = tid & 63, w = tid >> 6;
  const int wm = w >> 2, wn = w & 3;  // wave tile 32x64
  const int m0 = blockIdx.x * 64;
  const int arow = tid >> 4, ac4 = tid & 15;
  const int bn = tid >> 3, bg = tid & 7;
  const int lr = l & 15, lk = l >> 4;

  f32x4 zero = {0.f, 0.f, 0.f, 0.f};
  f32x4 acc[2][4];
#pragma unroll
  for (int i = 0; i < 2; i++)
#pragma unroll
    for (int j = 0; j < 4; j++) acc[i][j] = zero;

  for (int step = 0; step < 4; step++) {
#pragma unroll
    for (int i = 0; i < 2; i++) {
      int r = i * 32 + arow;
      size_t gi = (size_t)(m0 + r) * DIM + step * 64 + ac4 * 4;
      f32x4 v = *(const f32x4*)(P + gi);
      v += *(const f32x4*)(P + (size_t)NTOT * DIM + gi);
      unsigned lo = pack2bf(v.x, v.y);
      unsigned hi = pack2bf(v.z, v.w);
      int off = (r * 128 + ac4 * 8) ^ ((r & 7) << 4);
      *(unsigned long long*)(Ab + off) =
          (unsigned long long)lo | ((unsigned long long)hi << 32);
    }
#pragma unroll
    for (int i = 0; i < 4; i++) {
      int n = i * 64 + bn;
      i32x4 v = *(const i32x4*)(WT + (size_t)n * DIM + step * 64 + bg * 8);
      int off = (n * 128 + bg * 16) ^ ((n & 7) << 4);
      *(i32x4*)(Bb + off) = v;
    }
    __syncthreads();
#pragma unroll
    for (int kh = 0; kh < 2; kh++) {
      s16x8 af[2], bfr[4];
#pragma unroll
      for (int mt = 0; mt < 2; mt++) {
        int r = wm * 32 + mt * 16 + lr;
        int off = (r * 128 + kh * 64 + lk * 16) ^ ((r & 7) << 4);
        af[mt] = *(const s16x8*)(Ab + off);
      }
#pragma unroll
      for (int nt = 0; nt < 4; nt++) {
        int n = wn * 64 + nt * 16 + lr;
        int off = (n * 128 + kh * 64 + lk * 16) ^ ((n & 7) << 4);
        bfr[nt] = *(const s16x8*)(Bb + off);
      }
#pragma unroll
      for (int mt = 0; mt < 2; mt++)
#pragma unroll
        for (int nt = 0; nt < 4; nt++)
          acc[mt][nt] = __builtin_amdgcn_mfma_f32_16x16x32_bf16(af[mt], bfr[nt],
                                                                acc[mt][nt], 0, 0, 0);
    }
    __syncthreads();
  }
#pragma unroll
  for (int nt = 0; nt < 4; nt++) {
    int c = wn * 64 + nt * 16 + lr;
    float b = bias[c];
#pragma unroll
    for (int mt = 0; mt < 2; mt++) {
      int rbase = m0 + wm * 32 + mt * 16 + lk * 4;
#pragma unroll
      for (int j = 0; j < 4; j++) {
        float v = fmaxf(acc[mt][nt][j] + b, 0.f);
        out[(size_t)(rbase + j) * DIM + c] = f2bf(v);
      }
    }
  }
}

// ---------------- hidden: h = relu(x @ W1^T' + b1), W per row-half ----------------
__global__ __launch_bounds__(512) void mlp_hidden(const unsigned short* __restrict__ X,
                                                  const unsigned short* __restrict__ WTu,
                                                  const unsigned short* __restrict__ WTi,
                                                  const float* __restrict__ bu,
                                                  const float* __restrict__ bi,
                                                  unsigned short* __restrict__ out) {
  __shared__ char smem[40 * 1024];
  char* Ab = smem;
  char* Bb = smem + 8 * 1024;
  const int tid = threadIdx.x, l = tid & 63, w = tid >> 6;
  const int wm = w >> 2, wn = w & 3;
  const int m0 = blockIdx.x * 64;
  const unsigned short* WT = (m0 < NUSER) ? WTu : WTi;
  const float* bias = (m0 < NUSER) ? bu : bi;
  const int ar = tid >> 3, ag = tid & 7;
  const int bn = tid >> 3, bg = tid & 7;
  const int lr = l & 15, lk = l >> 4;

  f32x4 zero = {0.f, 0.f, 0.f, 0.f};
  f32x4 acc[2][4];
#pragma unroll
  for (int i = 0; i < 2; i++)
#pragma unroll
    for (int j = 0; j < 4; j++) acc[i][j] = zero;

  for (int step = 0; step < 4; step++) {
    {
      i32x4 v = *(const i32x4*)(X + (size_t)(m0 + ar) * DIM + step * 64 + ag * 8);
      int off = (ar * 128 + ag * 16) ^ ((ar & 7) << 4);
      *(i32x4*)(Ab + off) = v;
    }
#pragma unroll
    for (int i = 0; i < 4; i++) {
      int n = i * 64 + bn;
      i32x4 v = *(const i32x4*)(WT + (size_t)n * DIM + step * 64 + bg * 8);
      int off = (n * 128 + bg * 16) ^ ((n & 7) << 4);
      *(i32x4*)(Bb + off) = v;
    }
    __syncthreads();
#pragma unroll
    for (int kh = 0; kh < 2; kh++) {
      s16x8 af[2], bfr[4];
#pragma unroll
      for (int mt = 0; mt < 2; mt++) {
        int r = wm * 32 + mt * 16 + lr;
        int off = (r * 128 + kh * 64 + lk * 16) ^ ((r & 7) << 4);
        af[mt] = *(const s16x8*)(Ab + off);
      }
#pragma unroll
      for (int nt = 0; nt < 4; nt++) {
        int n = wn * 64 + nt * 16 + lr;
        int off = (n * 128 + kh * 64 + lk * 16) ^ ((n & 7) << 4);
        bfr[nt] = *(const s16x8*)(Bb + off);
      }
#pragma unroll
      for (int mt = 0; mt < 2; mt++)
#pragma unroll
        for (int nt = 0; nt < 4; nt++)
          acc[mt][nt] = __builtin_amdgcn_mfma_f32_16x16x32_bf16(af[mt], bfr[nt],
                                                                acc[mt][nt], 0, 0, 0);
    }
    __syncthreads();
  }
#pragma unroll
  for (int nt = 0; nt < 4; nt++) {
    int c = wn * 64 + nt * 16 + lr;
    float b = bias[c];
#pragma unroll
    for (int mt = 0; mt < 2; mt++) {
      int rbase = m0 + wm * 32 + mt * 16 + lk * 4;
#pragma unroll
      for (int j = 0; j < 4; j++) {
        float v = fmaxf(acc[mt][nt][j] + b, 0.f);
        out[(size_t)(rbase + j) * DIM + c] = f2bf(v);
      }
    }
  }
}

// ---------------- out layer + row-normalize -> un bf16 ----------------
__global__ __launch_bounds__(512) void mlp_out_norm(const unsigned short* __restrict__ H,
                                                    const unsigned short* __restrict__ WTu,
                                                    const unsigned short* __restrict__ WTi,
                                                    const float* __restrict__ bu,
                                                    const float* __restrict__ bi,
                                                    unsigned short* __restrict__ un) {
  __shared__ char smem[40 * 1024];
  __shared__ float rs[64][4];
  char* Ab = smem;
  char* Bb = smem + 8 * 1024;
  const int tid = threadIdx.x, l = tid & 63, w = tid >> 6;
  const int wm = w >> 2, wn = w & 3;
  const int m0 = blockIdx.x * 64;
  const unsigned short* WT = (m0 < NUSER) ? WTu : WTi;
  const float* bias = (m0 < NUSER) ? bu : bi;
  const int ar = tid >> 3, ag = tid & 7;
  const int bn = tid >> 3, bg = tid & 7;
  const int lr = l & 15, lk = l >> 4;

  f32x4 zero = {0.f, 0.f, 0.f, 0.f};
  f32x4 acc[2][4];
#pragma unroll
  for (int i = 0; i < 2; i++)
#pragma unroll
    for (int j = 0; j < 4; j++) acc[i][j] = zero;

  for (int step = 0; step < 4; step++) {
    {
      i32x4 v = *(const i32x4*)(H + (size_t)(m0 + ar) * DIM + step * 64 + ag * 8);
      int off = (ar * 128 + ag * 16) ^ ((ar & 7) << 4);
      *(i32x4*)(Ab + off) = v;
    }
#pragma unroll
    for (int i = 0; i < 4; i++) {
      int n = i * 64 + bn;
      i32x4 v = *(const i32x4*)(WT + (size_t)n * DIM + step * 64 + bg * 8);
      int off = (n * 128 + bg * 16) ^ ((n & 7) << 4);
      *(i32x4*)(Bb + off) = v;
    }
    __syncthreads();
#pragma unroll
    for (int kh = 0; kh < 2; kh++) {
      s16x8 af[2], bfr[4];
#pragma unroll
      for (int mt = 0; mt < 2; mt++) {
        int r = wm * 32 + mt * 16 + lr;
        int off = (r * 128 + kh * 64 + lk * 16) ^ ((r & 7) << 4);
        af[mt] = *(const s16x8*)(Ab + off);
      }
#pragma unroll
      for (int nt = 0; nt < 4; nt++) {
        int n = wn * 64 + nt * 16 + lr;
        int off = (n * 128 + kh * 64 + lk * 16) ^ ((n & 7) << 4);
        bfr[nt] = *(const s16x8*)(Bb + off);
      }
#pragma unroll
      for (int mt = 0; mt < 2; mt++)
#pragma unroll
        for (int nt = 0; nt < 4; nt++)
          acc[mt][nt] = __builtin_amdgcn_mfma_f32_16x16x32_bf16(af[mt], bfr[nt],
                                                                acc[mt][nt], 0, 0, 0);
    }
    __syncthreads();
  }

  float uval[2][4][4];
  float p[2][4];
#pragma unroll
  for (int mt = 0; mt < 2; mt++)
#pragma unroll
    for (int j = 0; j < 4; j++) p[mt][j] = 0.f;
#pragma unroll
  for (int nt = 0; nt < 4; nt++) {
    int c = wn * 64 + nt * 16 + lr;
    float b = bias[c];
#pragma unroll
    for (int mt = 0; mt < 2; mt++)
#pragma unroll
      for (int j = 0; j < 4; j++) {
        float v = acc[mt][nt][j] + b;
        uval[mt][nt][j] = v;
        p[mt][j] += v * v;
      }
  }
#pragma unroll
  for (int d = 1; d < 16; d <<= 1)
#pragma unroll
    for (int mt = 0; mt < 2; mt++)
#pragma unroll
      for (int j = 0; j < 4; j++) p[mt][j] += __shfl_xor(p[mt][j], d, 64);
  if (lr == 0) {
#pragma unroll
    for (int mt = 0; mt < 2; mt++)
#pragma unroll
      for (int j = 0; j < 4; j++) rs[wm * 32 + mt * 16 + lk * 4 + j][wn] = p[mt][j];
  }
  __syncthreads();
#pragma unroll
  for (int mt = 0; mt < 2; mt++) {
    int rl = wm * 32 + mt * 16 + lk * 4;
#pragma unroll
    for (int j = 0; j < 4; j++) {
      float tot = rs[rl + j][0] + rs[rl + j][1] + rs[rl + j][2] + rs[rl + j][3];
      float inv = 1.f / fmaxf(sqrtf(tot), 1e-8f);
#pragma unroll
      for (int nt = 0; nt < 4; nt++) {
        int c = wn * 64 + nt * 16 + lr;
        un[(size_t)(m0 + rl + j) * DIM + c] = f2bf(uval[mt][nt][j] * inv);
      }
    }
  }
}

// ---------------- sim = clip(un @ itn^T) ----------------
// Epilogue v2: stage C through LDS, store 2 full rows x 512 B per instruction.
__global__ __launch_bounds__(512) void simk(const unsigned short* __restrict__ UN,
                                            float* __restrict__ out) {
  __shared__ char smem[128 * 1024];
  char* Ab = smem;              // [128][256] bf16 64KB
  char* Bb = smem + 64 * 1024;  // [128][256] bf16 64KB
  const int tid = threadIdx.x, l = tid & 63, w = tid >> 6;
  const int wm = w >> 2, wn = w & 3;  // wave tile 64x32
  // XCD remap: each XCD owns a contiguous n-band (item rows L2-resident)
  const int lin = blockIdx.x + (blockIdx.y << 6);
  const int xcd = lin & 7, slot = lin >> 3;
  const int nblk = xcd * 8 + (slot & 7);
  const int mblk = slot >> 3;
  const int m0 = mblk * 128, n0 = nblk * 128;
  const int lr = l & 15, lk = l >> 4;
  const int sr = tid >> 5, sg = tid & 31;

#pragma unroll
  for (int i = 0; i < 8; i++) {
    int r = i * 16 + sr;
    i32x4 va = *(const i32x4*)(UN + (size_t)(m0 + r) * DIM + sg * 8);
    i32x4 vb = *(const i32x4*)(UN + (size_t)(NUSER + n0 + r) * DIM + sg * 8);
    int off = (r * 512 + sg * 16) ^ ((r & 7) << 4);
    *(i32x4*)(Ab + off) = va;
    *(i32x4*)(Bb + off) = vb;
  }
  __syncthreads();

  f32x4 zero = {0.f, 0.f, 0.f, 0.f};
  f32x4 acc[4][2];
#pragma unroll
  for (int i = 0; i < 4; i++)
#pragma unroll
    for (int j = 0; j < 2; j++) acc[i][j] = zero;

#pragma unroll
  for (int ks = 0; ks < 8; ks++) {
    s16x8 af[4], bfr[2];
#pragma unroll
    for (int mt = 0; mt < 4; mt++) {
      int r = wm * 64 + mt * 16 + lr;
      int off = (r * 512 + ks * 64 + lk * 16) ^ ((r & 7) << 4);
      af[mt] = *(const s16x8*)(Ab + off);
    }
#pragma unroll
    for (int nt = 0; nt < 2; nt++) {
      int n = wn * 32 + nt * 16 + lr;
      int off = (n * 512 + ks * 64 + lk * 16) ^ ((n & 7) << 4);
      bfr[nt] = *(const s16x8*)(Bb + off);
    }
#pragma unroll
    for (int mt = 0; mt < 4; mt++)
#pragma unroll
      for (int nt = 0; nt < 2; nt++)
        acc[mt][nt] = __builtin_amdgcn_mfma_f32_16x16x32_bf16(af[mt], bfr[nt],
                                                              acc[mt][nt], 0, 0, 0);
  }

  // epilogue: clamp -> LDS [128][132] f32 -> 512-B-contiguous row stores
  __syncthreads();
  float* T = (float*)smem;
#pragma unroll
  for (int mt = 0; mt < 4; mt++)
#pragma unroll
    for (int nt = 0; nt < 2; nt++)
#pragma unroll
      for (int j = 0; j < 4; j++) {
        int row = wm * 64 + mt * 16 + lk * 4 + j;
        int col = wn * 32 + nt * 16 + lr;
        T[row * 132 + col] = fminf(fmaxf(acc[mt][nt][j], 1e-6f), 1.0f);
      }
  __syncthreads();
  const int l5 = tid & 31, pg = tid >> 5;  // 16 row-groups x 8 rows
#pragma unroll
  for (int j = 0; j < 8; j++) {
    int row = pg * 8 + j;
    f32x4 v = *(const f32x4*)&T[row * 132 + l5 * 4];
    __builtin_nontemporal_store(
        v, (f32x4*)(out + (size_t)(m0 + row) * 8192 + n0 + l5 * 4));
  }
}

extern "C" void kernel_launch(void* const* d_in, const int* in_sizes, int n_in,
                              void* d_out, int out_size, void* d_ws, size_t ws_size,
                              hipStream_t stream) {
  const float* A    = (const float*)d_in[0];
  const float* feat = (const float*)d_in[1];
  const float* Wg   = (const float*)d_in[2];
  const float* bg   = (const float*)d_in[3];
  const float* uW1  = (const float*)d_in[4];
  const float* ub1  = (const float*)d_in[5];
  const float* uW2  = (const float*)d_in[6];
  const float* ub2  = (const float*)d_in[7];
  const float* iW1  = (const float*)d_in[8];
  const float* ib1  = (const float*)d_in[9];
  const float* iW2  = (const float*)d_in[10];
  const float* ib2  = (const float*)d_in[11];
  float* out = (float*)d_out;
  char* ob = (char*)d_out;

  // transient scratch inside d_out (dead before simk overwrites everything)
  float*          F1p  = (float*)(ob + 0);                 // 32 MiB: [2][16384][256] f32
  unsigned short* Ft   = (unsigned short*)(ob + 33554432); // 8 MiB: [256][16384] bf16
  unsigned short* WT5  = (unsigned short*)(ob + 41943040); // 5 x 128 KiB
  unsigned short* WgT  = WT5;
  unsigned short* uW1T = WT5 + 1 * 65536;
  unsigned short* uW2T = WT5 + 2 * 65536;
  unsigned short* iW1T = WT5 + 3 * 65536;
  unsigned short* iW2T = WT5 + 4 * 65536;
  unsigned short* Xb   = (unsigned short*)(ob + 41943040 + 655360);            // 8 MiB
  unsigned short* Hb   = (unsigned short*)(ob + 41943040 + 655360 + 8388608);  // 8 MiB
  unsigned short* UN   = (unsigned short*)d_ws;            // 8 MiB, survives into simk

  transpose_cvt<<<dim3(256, 4), 256, 0, stream>>>(feat, Ft, NTOT, DIM);
  transpose_w5<<<dim3(4, 4, 5), 256, 0, stream>>>(Wg, uW1, uW2, iW1, iW2, WT5);

  gemm1<<<dim3(512), 512, 0, stream>>>(A, Ft, F1p);
  mlp_in<<<dim3(256), 512, 0, stream>>>(F1p, WgT, bg, Xb);
  mlp_hidden<<<dim3(256), 512, 0, stream>>>(Xb, uW1T, iW1T, ub1, ib1, Hb);
  mlp_out_norm<<<dim3(256), 512, 0, stream>>>(Hb, uW2T, iW2T, ub2, ib2, UN);
  simk<<<dim3(64, 64), 512, 0, stream>>>(UN, out);
}

// Round 10
// 335.505 us; speedup vs baseline: 1.1886x; 1.1886x over previous
//
#include <hip/hip_runtime.h>
#include <hip/hip_bf16.h>

using f32x4 = __attribute__((ext_vector_type(4))) float;
using s16x8 = __attribute__((ext_vector_type(8))) short;
using i32x4 = __attribute__((ext_vector_type(4))) int;

#define NTOT 16384
#define NUSER 8192
#define DIM 256

__device__ __forceinline__ unsigned short f2bf(float f) {
  union { float f; unsigned u; } v; v.f = f;
  unsigned r = v.u + 0x7FFFu + ((v.u >> 16) & 1u);   // RNE
  return (unsigned short)(r >> 16);
}

__device__ __forceinline__ unsigned pack2bf(float x, float y) {
  float2 t; t.x = x; t.y = y;
  __hip_bfloat162 h = __float22bfloat162_rn(t);
  union { __hip_bfloat162 h; unsigned u; } cv; cv.h = h;
  return cv.u;
}

__device__ __forceinline__ void gload_lds16(const void* g, void* l) {
  __builtin_amdgcn_global_load_lds(
      (const __attribute__((address_space(1))) unsigned int*)g,
      (__attribute__((address_space(3))) unsigned int*)l, 16, 0, 0);
}

// ---------------- transpose + f32->bf16: dst[N][K] = src[K][N] ----------------
__global__ __launch_bounds__(256) void transpose_cvt(const float* __restrict__ src,
                                                     unsigned short* __restrict__ dst,
                                                     int K, int N) {
  __shared__ float tile[64][65];
  const int k0 = blockIdx.x * 64, n0 = blockIdx.y * 64;
  const int t = threadIdx.x;
#pragma unroll
  for (int i = 0; i < 16; i++) {
    int idx = i * 256 + t, r = idx >> 6, c = idx & 63;
    tile[r][c] = src[(size_t)(k0 + r) * N + n0 + c];
  }
  __syncthreads();
#pragma unroll
  for (int i = 0; i < 16; i++) {
    int idx = i * 256 + t, r = idx >> 6, c = idx & 63;
    dst[(size_t)(n0 + r) * K + k0 + c] = f2bf(tile[c][r]);
  }
}

// 5 square 256x256 weights in one launch
__global__ __launch_bounds__(256) void transpose_w5(const float* __restrict__ w0,
                                                    const float* __restrict__ w1,
                                                    const float* __restrict__ w2,
                                                    const float* __restrict__ w3,
                                                    const float* __restrict__ w4,
                                                    unsigned short* __restrict__ dstbase) {
  __shared__ float tile[64][65];
  const float* srcs[5] = {w0, w1, w2, w3, w4};
  const float* src = srcs[blockIdx.z];
  unsigned short* dst = dstbase + (size_t)blockIdx.z * 65536;
  const int k0 = blockIdx.x * 64, n0 = blockIdx.y * 64;
  const int t = threadIdx.x;
#pragma unroll
  for (int i = 0; i < 16; i++) {
    int idx = i * 256 + t, r = idx >> 6, c = idx & 63;
    tile[r][c] = src[(size_t)(k0 + r) * 256 + n0 + c];
  }
  __syncthreads();
#pragma unroll
  for (int i = 0; i < 16; i++) {
    int idx = i * 256 + t, r = idx >> 6, c = idx & 63;
    dst[(size_t)(n0 + r) * 256 + k0 + c] = f2bf(tile[c][r]);
  }
}

// ---------------- gemm1 (r6-exact): F1p[s] = A[:, sK:] @ feat[sK:, :] --------
// BM=128, BN=256, BK=64, split-K=2. grid 256 (1 block/CU), 512 thr.
// XCD remap: XCDs 0-3 own k-half 0, XCDs 4-7 own k-half 1 -> 4 MiB Ft slice
// is L2-resident per XCD. Counted-vmcnt 3-buffer pipeline (8 VMEM/step).
__global__ __launch_bounds__(512) void gemm1(const float* __restrict__ A,
                                             const unsigned short* __restrict__ Ft,
                                             float* __restrict__ F1p) {
  __shared__ char smem[144 * 1024];
  char* const Ab0 = smem;                 // [128][64] bf16, 16 KB each
  char* const Ab1 = smem + 16 * 1024;
  char* const Ab2 = smem + 32 * 1024;
  char* const Bb0 = smem + 48 * 1024;     // [256][64] bf16, 32 KB each
  char* const Bb1 = smem + 80 * 1024;
  char* const Bb2 = smem + 112 * 1024;

  const int tid = threadIdx.x;
  const int l = tid & 63, w = tid >> 6;
  const int wm = w >> 2, wn = w & 3;      // 2x4 waves, wave tile 64x64
  const int lr = l & 15, lk = l >> 4;

  const int lin = blockIdx.x;             // 0..255
  const int xcd = lin & 7, slot = lin >> 3;   // slot 0..31
  const int ks = xcd >> 2;                // 0..1
  const int mblk = (xcd & 3) * 32 + slot; // 0..127
  const int m0 = mblk * 128;
  const size_t ks0 = (size_t)ks * 8192;
  float* out = F1p + (size_t)ks * NTOT * DIM;

  // A staging: 128 rows x 64 f32 per step = 4 sub-loads of 16B/thread,
  // lane-contiguous: sub-load j covers rows j*32..j*32+31.
  const int arow = tid >> 4, ac16 = tid & 15;   // row-in-32, 16B chunk
  const float* asrc = A + (size_t)(m0 + arow) * NTOT + ks0 + ac16 * 4;
  int aoff[4];
#pragma unroll
  for (int j = 0; j < 4; j++) {
    int r = j * 32 + arow;
    aoff[j] = r * 128 + ((ac16 * 8) ^ ((r & 7) << 4));
  }

  // B staging via global_load_lds: per wave 4 x 1KB (rows w*32..w*32+31)
  const int brin = l >> 3;
  const int bldso = w * 4096;
  const char* bsrc = (const char*)Ft + (size_t)(w * 32 + brin) * (NTOT * 2) +
                     ks0 * 2 + (((l & 7) * 16) ^ (brin << 4));

  f32x4 zero = {0.f, 0.f, 0.f, 0.f};
  f32x4 acc[4][4];
#pragma unroll
  for (int i = 0; i < 4; i++)
#pragma unroll
    for (int j = 0; j < 4; j++) acc[i][j] = zero;

  struct AQuad { f32x4 v[4]; };
  AQuad av0, av1, av2;

  auto issueB = [&](int t, char* Bb) {
#pragma unroll
    for (int i = 0; i < 4; i++)
      gload_lds16(bsrc + (size_t)i * 8 * (NTOT * 2) + t * 128,
                  Bb + bldso + i * 1024);
  };
  auto loadA = [&](int t, AQuad& s) {
#pragma unroll
    for (int j = 0; j < 4; j++)
      s.v[j] = __builtin_nontemporal_load(
          (const f32x4*)(asrc + (size_t)j * 32 * NTOT + t * 64));
  };
  auto writeA = [&](const AQuad& s, char* Ab) {
#pragma unroll
    for (int j = 0; j < 4; j++) {
      unsigned lo = pack2bf(s.v[j].x, s.v[j].y);
      unsigned hi = pack2bf(s.v[j].z, s.v[j].w);
      *(unsigned long long*)(Ab + aoff[j]) =
          (unsigned long long)lo | ((unsigned long long)hi << 32);
    }
  };
  auto compute = [&](const char* Ab, const char* Bb) {
#pragma unroll
    for (int kh = 0; kh < 2; kh++) {
      s16x8 af[4], bf[4];
#pragma unroll
      for (int mt = 0; mt < 4; mt++) {
        int r = wm * 64 + mt * 16 + lr;
        int off = r * 128 + ((kh * 64 + lk * 16) ^ ((r & 7) << 4));
        af[mt] = *(const s16x8*)(Ab + off);
      }
#pragma unroll
      for (int nt = 0; nt < 4; nt++) {
        int n = wn * 64 + nt * 16 + lr;
        int off = n * 128 + ((kh * 64 + lk * 16) ^ ((n & 7) << 4));
        bf[nt] = *(const s16x8*)(Bb + off);
      }
#pragma unroll
      for (int mt = 0; mt < 4; mt++)
#pragma unroll
        for (int nt = 0; nt < 4; nt++)
          acc[mt][nt] = __builtin_amdgcn_mfma_f32_16x16x32_bf16(af[mt], bf[nt],
                                                                acc[mt][nt], 0, 0, 0);
    }
  };

#define STEP_BAR(N)                                                \
  asm volatile("s_waitcnt vmcnt(" #N ") lgkmcnt(0)" ::: "memory"); \
  __builtin_amdgcn_s_barrier();                                    \
  __builtin_amdgcn_sched_barrier(0);

  // prologue: steps 0,1 in flight; write A(0)
  issueB(0, Bb0);
  loadA(0, av0);
  issueB(1, Bb1);
  loadA(1, av1);
  writeA(av0, Ab0);
  STEP_BAR(8)

  // steady state: 42 x 3 phases = steps 0..125 (128 total K-steps)
  for (int t = 0; t < 126; t += 3) {
    issueB(t + 2, Bb2);
    loadA(t + 2, av2);
    compute(Ab0, Bb0);
    writeA(av1, Ab1);
    STEP_BAR(8)
    issueB(t + 3, Bb0);
    loadA(t + 3, av0);
    compute(Ab1, Bb1);
    writeA(av2, Ab2);
    STEP_BAR(8)
    issueB(t + 4, Bb1);
    loadA(t + 4, av1);
    compute(Ab2, Bb2);
    writeA(av0, Ab0);
    STEP_BAR(8)
  }
  // step 126 (cur=buf0; B(126) in Bb0, B(127) in Bb1 already issued)
  compute(Ab0, Bb0);
  writeA(av1, Ab1);
  STEP_BAR(0)
  // step 127
  compute(Ab1, Bb1);
#undef STEP_BAR

#pragma unroll
  for (int mt = 0; mt < 4; mt++) {
    int rbase = m0 + wm * 64 + mt * 16 + lk * 4;
#pragma unroll
    for (int nt = 0; nt < 4; nt++) {
      int c = wn * 64 + nt * 16 + lr;
#pragma unroll
      for (int j = 0; j < 4; j++)
        __builtin_nontemporal_store(acc[mt][nt][j],
                                    out + (size_t)(rbase + j) * DIM + c);
    }
  }
}

// ---------------- stage2: x = relu((P0+P1) @ WgT^T + bg) -> bf16 ----------------
__global__ __launch_bounds__(512) void mlp_in(const float* __restrict__ P,
                                              const unsigned short* __restrict__ WT,
                                              const float* __restrict__ bias,
                                              unsigned short* __restrict__ out) {
  __shared__ char smem[40 * 1024];
  char* Ab = smem;             // [64][64] bf16 8KB
  char* Bb = smem + 8 * 1024;  // [256][64] bf16 32KB
  const int tid = threadIdx.x, l = tid & 63, w = tid >> 6;
  const int wm = w >> 2, wn = w & 3;  // wave tile 32x64
  const int m0 = blockIdx.x * 64;
  const int arow = tid >> 4, ac4 = tid & 15;
  const int bn = tid >> 3, bg = tid & 7;
  const int lr = l & 15, lk = l >> 4;

  f32x4 zero = {0.f, 0.f, 0.f, 0.f};
  f32x4 acc[2][4];
#pragma unroll
  for (int i = 0; i < 2; i++)
#pragma unroll
    for (int j = 0; j < 4; j++) acc[i][j] = zero;

  for (int step = 0; step < 4; step++) {
#pragma unroll
    for (int i = 0; i < 2; i++) {
      int r = i * 32 + arow;
      size_t gi = (size_t)(m0 + r) * DIM + step * 64 + ac4 * 4;
      f32x4 v = *(const f32x4*)(P + gi);
      v += *(const f32x4*)(P + (size_t)NTOT * DIM + gi);
      unsigned lo = pack2bf(v.x, v.y);
      unsigned hi = pack2bf(v.z, v.w);
      int off = (r * 128 + ac4 * 8) ^ ((r & 7) << 4);
      *(unsigned long long*)(Ab + off) =
          (unsigned long long)lo | ((unsigned long long)hi << 32);
    }
#pragma unroll
    for (int i = 0; i < 4; i++) {
      int n = i * 64 + bn;
      i32x4 v = *(const i32x4*)(WT + (size_t)n * DIM + step * 64 + bg * 8);
      int off = (n * 128 + bg * 16) ^ ((n & 7) << 4);
      *(i32x4*)(Bb + off) = v;
    }
    __syncthreads();
#pragma unroll
    for (int kh = 0; kh < 2; kh++) {
      s16x8 af[2], bfr[4];
#pragma unroll
      for (int mt = 0; mt < 2; mt++) {
        int r = wm * 32 + mt * 16 + lr;
        int off = (r * 128 + kh * 64 + lk * 16) ^ ((r & 7) << 4);
        af[mt] = *(const s16x8*)(Ab + off);
      }
#pragma unroll
      for (int nt = 0; nt < 4; nt++) {
        int n = wn * 64 + nt * 16 + lr;
        int off = (n * 128 + kh * 64 + lk * 16) ^ ((n & 7) << 4);
        bfr[nt] = *(const s16x8*)(Bb + off);
      }
#pragma unroll
      for (int mt = 0; mt < 2; mt++)
#pragma unroll
        for (int nt = 0; nt < 4; nt++)
          acc[mt][nt] = __builtin_amdgcn_mfma_f32_16x16x32_bf16(af[mt], bfr[nt],
                                                                acc[mt][nt], 0, 0, 0);
    }
    __syncthreads();
  }
#pragma unroll
  for (int nt = 0; nt < 4; nt++) {
    int c = wn * 64 + nt * 16 + lr;
    float b = bias[c];
#pragma unroll
    for (int mt = 0; mt < 2; mt++) {
      int rbase = m0 + wm * 32 + mt * 16 + lk * 4;
#pragma unroll
      for (int j = 0; j < 4; j++) {
        float v = fmaxf(acc[mt][nt][j] + b, 0.f);
        out[(size_t)(rbase + j) * DIM + c] = f2bf(v);
      }
    }
  }
}

// ---------------- hidden: h = relu(x @ W1^T' + b1), W per row-half ----------------
__global__ __launch_bounds__(512) void mlp_hidden(const unsigned short* __restrict__ X,
                                                  const unsigned short* __restrict__ WTu,
                                                  const unsigned short* __restrict__ WTi,
                                                  const float* __restrict__ bu,
                                                  const float* __restrict__ bi,
                                                  unsigned short* __restrict__ out) {
  __shared__ char smem[40 * 1024];
  char* Ab = smem;
  char* Bb = smem + 8 * 1024;
  const int tid = threadIdx.x, l = tid & 63, w = tid >> 6;
  const int wm = w >> 2, wn = w & 3;
  const int m0 = blockIdx.x * 64;
  const unsigned short* WT = (m0 < NUSER) ? WTu : WTi;
  const float* bias = (m0 < NUSER) ? bu : bi;
  const int ar = tid >> 3, ag = tid & 7;
  const int bn = tid >> 3, bg = tid & 7;
  const int lr = l & 15, lk = l >> 4;

  f32x4 zero = {0.f, 0.f, 0.f, 0.f};
  f32x4 acc[2][4];
#pragma unroll
  for (int i = 0; i < 2; i++)
#pragma unroll
    for (int j = 0; j < 4; j++) acc[i][j] = zero;

  for (int step = 0; step < 4; step++) {
    {
      i32x4 v = *(const i32x4*)(X + (size_t)(m0 + ar) * DIM + step * 64 + ag * 8);
      int off = (ar * 128 + ag * 16) ^ ((ar & 7) << 4);
      *(i32x4*)(Ab + off) = v;
    }
#pragma unroll
    for (int i = 0; i < 4; i++) {
      int n = i * 64 + bn;
      i32x4 v = *(const i32x4*)(WT + (size_t)n * DIM + step * 64 + bg * 8);
      int off = (n * 128 + bg * 16) ^ ((n & 7) << 4);
      *(i32x4*)(Bb + off) = v;
    }
    __syncthreads();
#pragma unroll
    for (int kh = 0; kh < 2; kh++) {
      s16x8 af[2], bfr[4];
#pragma unroll
      for (int mt = 0; mt < 2; mt++) {
        int r = wm * 32 + mt * 16 + lr;
        int off = (r * 128 + kh * 64 + lk * 16) ^ ((r & 7) << 4);
        af[mt] = *(const s16x8*)(Ab + off);
      }
#pragma unroll
      for (int nt = 0; nt < 4; nt++) {
        int n = wn * 64 + nt * 16 + lr;
        int off = (n * 128 + kh * 64 + lk * 16) ^ ((n & 7) << 4);
        bfr[nt] = *(const s16x8*)(Bb + off);
      }
#pragma unroll
      for (int mt = 0; mt < 2; mt++)
#pragma unroll
        for (int nt = 0; nt < 4; nt++)
          acc[mt][nt] = __builtin_amdgcn_mfma_f32_16x16x32_bf16(af[mt], bfr[nt],
                                                                acc[mt][nt], 0, 0, 0);
    }
    __syncthreads();
  }
#pragma unroll
  for (int nt = 0; nt < 4; nt++) {
    int c = wn * 64 + nt * 16 + lr;
    float b = bias[c];
#pragma unroll
    for (int mt = 0; mt < 2; mt++) {
      int rbase = m0 + wm * 32 + mt * 16 + lk * 4;
#pragma unroll
      for (int j = 0; j < 4; j++) {
        float v = fmaxf(acc[mt][nt][j] + b, 0.f);
        out[(size_t)(rbase + j) * DIM + c] = f2bf(v);
      }
    }
  }
}

// ---------------- out layer + row-normalize -> un bf16 ----------------
__global__ __launch_bounds__(512) void mlp_out_norm(const unsigned short* __restrict__ H,
                                                    const unsigned short* __restrict__ WTu,
                                                    const unsigned short* __restrict__ WTi,
                                                    const float* __restrict__ bu,
                                                    const float* __restrict__ bi,
                                                    unsigned short* __restrict__ un) {
  __shared__ char smem[40 * 1024];
  __shared__ float rs[64][4];
  char* Ab = smem;
  char* Bb = smem + 8 * 1024;
  const int tid = threadIdx.x, l = tid & 63, w = tid >> 6;
  const int wm = w >> 2, wn = w & 3;
  const int m0 = blockIdx.x * 64;
  const unsigned short* WT = (m0 < NUSER) ? WTu : WTi;
  const float* bias = (m0 < NUSER) ? bu : bi;
  const int ar = tid >> 3, ag = tid & 7;
  const int bn = tid >> 3, bg = tid & 7;
  const int lr = l & 15, lk = l >> 4;

  f32x4 zero = {0.f, 0.f, 0.f, 0.f};
  f32x4 acc[2][4];
#pragma unroll
  for (int i = 0; i < 2; i++)
#pragma unroll
    for (int j = 0; j < 4; j++) acc[i][j] = zero;

  for (int step = 0; step < 4; step++) {
    {
      i32x4 v = *(const i32x4*)(H + (size_t)(m0 + ar) * DIM + step * 64 + ag * 8);
      int off = (ar * 128 + ag * 16) ^ ((ar & 7) << 4);
      *(i32x4*)(Ab + off) = v;
    }
#pragma unroll
    for (int i = 0; i < 4; i++) {
      int n = i * 64 + bn;
      i32x4 v = *(const i32x4*)(WT + (size_t)n * DIM + step * 64 + bg * 8);
      int off = (n * 128 + bg * 16) ^ ((n & 7) << 4);
      *(i32x4*)(Bb + off) = v;
    }
    __syncthreads();
#pragma unroll
    for (int kh = 0; kh < 2; kh++) {
      s16x8 af[2], bfr[4];
#pragma unroll
      for (int mt = 0; mt < 2; mt++) {
        int r = wm * 32 + mt * 16 + lr;
        int off = (r * 128 + kh * 64 + lk * 16) ^ ((r & 7) << 4);
        af[mt] = *(const s16x8*)(Ab + off);
      }
#pragma unroll
      for (int nt = 0; nt < 4; nt++) {
        int n = wn * 64 + nt * 16 + lr;
        int off = (n * 128 + kh * 64 + lk * 16) ^ ((n & 7) << 4);
        bfr[nt] = *(const s16x8*)(Bb + off);
      }
#pragma unroll
      for (int mt = 0; mt < 2; mt++)
#pragma unroll
        for (int nt = 0; nt < 4; nt++)
          acc[mt][nt] = __builtin_amdgcn_mfma_f32_16x16x32_bf16(af[mt], bfr[nt],
                                                                acc[mt][nt], 0, 0, 0);
    }
    __syncthreads();
  }

  float uval[2][4][4];
  float p[2][4];
#pragma unroll
  for (int mt = 0; mt < 2; mt++)
#pragma unroll
    for (int j = 0; j < 4; j++) p[mt][j] = 0.f;
#pragma unroll
  for (int nt = 0; nt < 4; nt++) {
    int c = wn * 64 + nt * 16 + lr;
    float b = bias[c];
#pragma unroll
    for (int mt = 0; mt < 2; mt++)
#pragma unroll
      for (int j = 0; j < 4; j++) {
        float v = acc[mt][nt][j] + b;
        uval[mt][nt][j] = v;
        p[mt][j] += v * v;
      }
  }
#pragma unroll
  for (int d = 1; d < 16; d <<= 1)
#pragma unroll
    for (int mt = 0; mt < 2; mt++)
#pragma unroll
      for (int j = 0; j < 4; j++) p[mt][j] += __shfl_xor(p[mt][j], d, 64);
  if (lr == 0) {
#pragma unroll
    for (int mt = 0; mt < 2; mt++)
#pragma unroll
      for (int j = 0; j < 4; j++) rs[wm * 32 + mt * 16 + lk * 4 + j][wn] = p[mt][j];
  }
  __syncthreads();
#pragma unroll
  for (int mt = 0; mt < 2; mt++) {
    int rl = wm * 32 + mt * 16 + lk * 4;
#pragma unroll
    for (int j = 0; j < 4; j++) {
      float tot = rs[rl + j][0] + rs[rl + j][1] + rs[rl + j][2] + rs[rl + j][3];
      float inv = 1.f / fmaxf(sqrtf(tot), 1e-8f);
#pragma unroll
      for (int nt = 0; nt < 4; nt++) {
        int c = wn * 64 + nt * 16 + lr;
        un[(size_t)(m0 + rl + j) * DIM + c] = f2bf(uval[mt][nt][j] * inv);
      }
    }
  }
}

// ---------------- sim = clip(un @ itn^T) ----------------
// LDS-staged epilogue: 512-B-contiguous row stores.
__global__ __launch_bounds__(512) void simk(const unsigned short* __restrict__ UN,
                                            float* __restrict__ out) {
  __shared__ char smem[128 * 1024];
  char* Ab = smem;              // [128][256] bf16 64KB
  char* Bb = smem + 64 * 1024;  // [128][256] bf16 64KB
  const int tid = threadIdx.x, l = tid & 63, w = tid >> 6;
  const int wm = w >> 2, wn = w & 3;  // wave tile 64x32
  // XCD remap: each XCD owns a contiguous n-band (item rows L2-resident)
  const int lin = blockIdx.x + (blockIdx.y << 6);
  const int xcd = lin & 7, slot = lin >> 3;
  const int nblk = xcd * 8 + (slot & 7);
  const int mblk = slot >> 3;
  const int m0 = mblk * 128, n0 = nblk * 128;
  const int lr = l & 15, lk = l >> 4;
  const int sr = tid >> 5, sg = tid & 31;

#pragma unroll
  for (int i = 0; i < 8; i++) {
    int r = i * 16 + sr;
    i32x4 va = *(const i32x4*)(UN + (size_t)(m0 + r) * DIM + sg * 8);
    i32x4 vb = *(const i32x4*)(UN + (size_t)(NUSER + n0 + r) * DIM + sg * 8);
    int off = (r * 512 + sg * 16) ^ ((r & 7) << 4);
    *(i32x4*)(Ab + off) = va;
    *(i32x4*)(Bb + off) = vb;
  }
  __syncthreads();

  f32x4 zero = {0.f, 0.f, 0.f, 0.f};
  f32x4 acc[4][2];
#pragma unroll
  for (int i = 0; i < 4; i++)
#pragma unroll
    for (int j = 0; j < 2; j++) acc[i][j] = zero;

#pragma unroll
  for (int ks = 0; ks < 8; ks++) {
    s16x8 af[4], bfr[2];
#pragma unroll
    for (int mt = 0; mt < 4; mt++) {
      int r = wm * 64 + mt * 16 + lr;
      int off = (r * 512 + ks * 64 + lk * 16) ^ ((r & 7) << 4);
      af[mt] = *(const s16x8*)(Ab + off);
    }
#pragma unroll
    for (int nt = 0; nt < 2; nt++) {
      int n = wn * 32 + nt * 16 + lr;
      int off = (n * 512 + ks * 64 + lk * 16) ^ ((n & 7) << 4);
      bfr[nt] = *(const s16x8*)(Bb + off);
    }
#pragma unroll
    for (int mt = 0; mt < 4; mt++)
#pragma unroll
      for (int nt = 0; nt < 2; nt++)
        acc[mt][nt] = __builtin_amdgcn_mfma_f32_16x16x32_bf16(af[mt], bfr[nt],
                                                              acc[mt][nt], 0, 0, 0);
  }

  // epilogue: clamp -> LDS [128][132] f32 -> 512-B-contiguous row stores
  __syncthreads();
  float* T = (float*)smem;
#pragma unroll
  for (int mt = 0; mt < 4; mt++)
#pragma unroll
    for (int nt = 0; nt < 2; nt++)
#pragma unroll
      for (int j = 0; j < 4; j++) {
        int row = wm * 64 + mt * 16 + lk * 4 + j;
        int col = wn * 32 + nt * 16 + lr;
        T[row * 132 + col] = fminf(fmaxf(acc[mt][nt][j], 1e-6f), 1.0f);
      }
  __syncthreads();
  const int l5 = tid & 31, pg = tid >> 5;  // 16 row-groups x 8 rows
#pragma unroll
  for (int j = 0; j < 8; j++) {
    int row = pg * 8 + j;
    f32x4 v = *(const f32x4*)&T[row * 132 + l5 * 4];
    __builtin_nontemporal_store(
        v, (f32x4*)(out + (size_t)(m0 + row) * 8192 + n0 + l5 * 4));
  }
}

extern "C" void kernel_launch(void* const* d_in, const int* in_sizes, int n_in,
                              void* d_out, int out_size, void* d_ws, size_t ws_size,
                              hipStream_t stream) {
  const float* A    = (const float*)d_in[0];
  const float* feat = (const float*)d_in[1];
  const float* Wg   = (const float*)d_in[2];
  const float* bg   = (const float*)d_in[3];
  const float* uW1  = (const float*)d_in[4];
  const float* ub1  = (const float*)d_in[5];
  const float* uW2  = (const float*)d_in[6];
  const float* ub2  = (const float*)d_in[7];
  const float* iW1  = (const float*)d_in[8];
  const float* ib1  = (const float*)d_in[9];
  const float* iW2  = (const float*)d_in[10];
  const float* ib2  = (const float*)d_in[11];
  float* out = (float*)d_out;
  char* ob = (char*)d_out;

  // transient scratch inside d_out (dead before simk overwrites everything)
  float*          F1p  = (float*)(ob + 0);                 // 32 MiB: [2][16384][256] f32
  unsigned short* Ft   = (unsigned short*)(ob + 33554432); // 8 MiB: [256][16384] bf16
  unsigned short* WT5  = (unsigned short*)(ob + 41943040); // 5 x 128 KiB
  unsigned short* WgT  = WT5;
  unsigned short* uW1T = WT5 + 1 * 65536;
  unsigned short* uW2T = WT5 + 2 * 65536;
  unsigned short* iW1T = WT5 + 3 * 65536;
  unsigned short* iW2T = WT5 + 4 * 65536;
  unsigned short* Xb   = (unsigned short*)(ob + 41943040 + 655360);            // 8 MiB
  unsigned short* Hb   = (unsigned short*)(ob + 41943040 + 655360 + 8388608);  // 8 MiB
  unsigned short* UN   = (unsigned short*)d_ws;            // 8 MiB, survives into simk

  transpose_cvt<<<dim3(256, 4), 256, 0, stream>>>(feat, Ft, NTOT, DIM);
  transpose_w5<<<dim3(4, 4, 5), 256, 0, stream>>>(Wg, uW1, uW2, iW1, iW2, WT5);

  gemm1<<<dim3(256), 512, 0, stream>>>(A, Ft, F1p);
  mlp_in<<<dim3(256), 512, 0, stream>>>(F1p, WgT, bg, Xb);
  mlp_hidden<<<dim3(256), 512, 0, stream>>>(Xb, uW1T, iW1T, ub1, ib1, Hb);
  mlp_out_norm<<<dim3(256), 512, 0, stream>>>(Hb, uW2T, iW2T, ub2, ib2, UN);
  simk<<<dim3(64, 64), 512, 0, stream>>>(UN, out);
}

// Round 11
// 320.817 us; speedup vs baseline: 1.2430x; 1.0458x over previous
//
#include <hip/hip_runtime.h>
#include <hip/hip_bf16.h>

using f32x4 = __attribute__((ext_vector_type(4))) float;
using s16x8 = __attribute__((ext_vector_type(8))) short;
using i32x4 = __attribute__((ext_vector_type(4))) int;

#define NTOT 16384
#define NUSER 8192
#define DIM 256

__device__ __forceinline__ unsigned short f2bf(float f) {
  union { float f; unsigned u; } v; v.f = f;
  unsigned r = v.u + 0x7FFFu + ((v.u >> 16) & 1u);   // RNE
  return (unsigned short)(r >> 16);
}

__device__ __forceinline__ unsigned pack2bf(float x, float y) {
  float2 t; t.x = x; t.y = y;
  __hip_bfloat162 h = __float22bfloat162_rn(t);
  union { __hip_bfloat162 h; unsigned u; } cv; cv.h = h;
  return cv.u;
}

__device__ __forceinline__ void gload_lds16(const void* g, void* l) {
  __builtin_amdgcn_global_load_lds(
      (const __attribute__((address_space(1))) unsigned int*)g,
      (__attribute__((address_space(3))) unsigned int*)l, 16, 0, 0);
}

// ---------------- transpose + f32->bf16: dst[N][K] = src[K][N] ----------------
__global__ __launch_bounds__(256) void transpose_cvt(const float* __restrict__ src,
                                                     unsigned short* __restrict__ dst,
                                                     int K, int N) {
  __shared__ float tile[64][65];
  const int k0 = blockIdx.x * 64, n0 = blockIdx.y * 64;
  const int t = threadIdx.x;
#pragma unroll
  for (int i = 0; i < 16; i++) {
    int idx = i * 256 + t, r = idx >> 6, c = idx & 63;
    tile[r][c] = src[(size_t)(k0 + r) * N + n0 + c];
  }
  __syncthreads();
#pragma unroll
  for (int i = 0; i < 16; i++) {
    int idx = i * 256 + t, r = idx >> 6, c = idx & 63;
    dst[(size_t)(n0 + r) * K + k0 + c] = f2bf(tile[c][r]);
  }
}

// 5 square 256x256 weights in one launch
__global__ __launch_bounds__(256) void transpose_w5(const float* __restrict__ w0,
                                                    const float* __restrict__ w1,
                                                    const float* __restrict__ w2,
                                                    const float* __restrict__ w3,
                                                    const float* __restrict__ w4,
                                                    unsigned short* __restrict__ dstbase) {
  __shared__ float tile[64][65];
  const float* srcs[5] = {w0, w1, w2, w3, w4};
  const float* src = srcs[blockIdx.z];
  unsigned short* dst = dstbase + (size_t)blockIdx.z * 65536;
  const int k0 = blockIdx.x * 64, n0 = blockIdx.y * 64;
  const int t = threadIdx.x;
#pragma unroll
  for (int i = 0; i < 16; i++) {
    int idx = i * 256 + t, r = idx >> 6, c = idx & 63;
    tile[r][c] = src[(size_t)(k0 + r) * 256 + n0 + c];
  }
  __syncthreads();
#pragma unroll
  for (int i = 0; i < 16; i++) {
    int idx = i * 256 + t, r = idx >> 6, c = idx & 63;
    dst[(size_t)(n0 + r) * 256 + k0 + c] = f2bf(tile[c][r]);
  }
}

// ---------------- gemm1 (r6-exact): F1p[s] = A[:, sK:] @ feat[sK:, :] --------
__global__ __launch_bounds__(512) void gemm1(const float* __restrict__ A,
                                             const unsigned short* __restrict__ Ft,
                                             float* __restrict__ F1p) {
  __shared__ char smem[144 * 1024];
  char* const Ab0 = smem;                 // [128][64] bf16, 16 KB each
  char* const Ab1 = smem + 16 * 1024;
  char* const Ab2 = smem + 32 * 1024;
  char* const Bb0 = smem + 48 * 1024;     // [256][64] bf16, 32 KB each
  char* const Bb1 = smem + 80 * 1024;
  char* const Bb2 = smem + 112 * 1024;

  const int tid = threadIdx.x;
  const int l = tid & 63, w = tid >> 6;
  const int wm = w >> 2, wn = w & 3;      // 2x4 waves, wave tile 64x64
  const int lr = l & 15, lk = l >> 4;

  const int lin = blockIdx.x;             // 0..255
  const int xcd = lin & 7, slot = lin >> 3;   // slot 0..31
  const int ks = xcd >> 2;                // 0..1
  const int mblk = (xcd & 3) * 32 + slot; // 0..127
  const int m0 = mblk * 128;
  const size_t ks0 = (size_t)ks * 8192;
  float* out = F1p + (size_t)ks * NTOT * DIM;

  const int arow = tid >> 4, ac16 = tid & 15;   // row-in-32, 16B chunk
  const float* asrc = A + (size_t)(m0 + arow) * NTOT + ks0 + ac16 * 4;
  int aoff[4];
#pragma unroll
  for (int j = 0; j < 4; j++) {
    int r = j * 32 + arow;
    aoff[j] = r * 128 + ((ac16 * 8) ^ ((r & 7) << 4));
  }

  const int brin = l >> 3;
  const int bldso = w * 4096;
  const char* bsrc = (const char*)Ft + (size_t)(w * 32 + brin) * (NTOT * 2) +
                     ks0 * 2 + (((l & 7) * 16) ^ (brin << 4));

  f32x4 zero = {0.f, 0.f, 0.f, 0.f};
  f32x4 acc[4][4];
#pragma unroll
  for (int i = 0; i < 4; i++)
#pragma unroll
    for (int j = 0; j < 4; j++) acc[i][j] = zero;

  struct AQuad { f32x4 v[4]; };
  AQuad av0, av1, av2;

  auto issueB = [&](int t, char* Bb) {
#pragma unroll
    for (int i = 0; i < 4; i++)
      gload_lds16(bsrc + (size_t)i * 8 * (NTOT * 2) + t * 128,
                  Bb + bldso + i * 1024);
  };
  auto loadA = [&](int t, AQuad& s) {
#pragma unroll
    for (int j = 0; j < 4; j++)
      s.v[j] = __builtin_nontemporal_load(
          (const f32x4*)(asrc + (size_t)j * 32 * NTOT + t * 64));
  };
  auto writeA = [&](const AQuad& s, char* Ab) {
#pragma unroll
    for (int j = 0; j < 4; j++) {
      unsigned lo = pack2bf(s.v[j].x, s.v[j].y);
      unsigned hi = pack2bf(s.v[j].z, s.v[j].w);
      *(unsigned long long*)(Ab + aoff[j]) =
          (unsigned long long)lo | ((unsigned long long)hi << 32);
    }
  };
  auto compute = [&](const char* Ab, const char* Bb) {
#pragma unroll
    for (int kh = 0; kh < 2; kh++) {
      s16x8 af[4], bf[4];
#pragma unroll
      for (int mt = 0; mt < 4; mt++) {
        int r = wm * 64 + mt * 16 + lr;
        int off = r * 128 + ((kh * 64 + lk * 16) ^ ((r & 7) << 4));
        af[mt] = *(const s16x8*)(Ab + off);
      }
#pragma unroll
      for (int nt = 0; nt < 4; nt++) {
        int n = wn * 64 + nt * 16 + lr;
        int off = n * 128 + ((kh * 64 + lk * 16) ^ ((n & 7) << 4));
        bf[nt] = *(const s16x8*)(Bb + off);
      }
#pragma unroll
      for (int mt = 0; mt < 4; mt++)
#pragma unroll
        for (int nt = 0; nt < 4; nt++)
          acc[mt][nt] = __builtin_amdgcn_mfma_f32_16x16x32_bf16(af[mt], bf[nt],
                                                                acc[mt][nt], 0, 0, 0);
    }
  };

#define STEP_BAR(N)                                                \
  asm volatile("s_waitcnt vmcnt(" #N ") lgkmcnt(0)" ::: "memory"); \
  __builtin_amdgcn_s_barrier();                                    \
  __builtin_amdgcn_sched_barrier(0);

  issueB(0, Bb0);
  loadA(0, av0);
  issueB(1, Bb1);
  loadA(1, av1);
  writeA(av0, Ab0);
  STEP_BAR(8)

  for (int t = 0; t < 126; t += 3) {
    issueB(t + 2, Bb2);
    loadA(t + 2, av2);
    compute(Ab0, Bb0);
    writeA(av1, Ab1);
    STEP_BAR(8)
    issueB(t + 3, Bb0);
    loadA(t + 3, av0);
    compute(Ab1, Bb1);
    writeA(av2, Ab2);
    STEP_BAR(8)
    issueB(t + 4, Bb1);
    loadA(t + 4, av1);
    compute(Ab2, Bb2);
    writeA(av0, Ab0);
    STEP_BAR(8)
  }
  compute(Ab0, Bb0);
  writeA(av1, Ab1);
  STEP_BAR(0)
  compute(Ab1, Bb1);
#undef STEP_BAR

#pragma unroll
  for (int mt = 0; mt < 4; mt++) {
    int rbase = m0 + wm * 64 + mt * 16 + lk * 4;
#pragma unroll
    for (int nt = 0; nt < 4; nt++) {
      int c = wn * 64 + nt * 16 + lr;
#pragma unroll
      for (int j = 0; j < 4; j++)
        __builtin_nontemporal_store(acc[mt][nt][j],
                                    out + (size_t)(rbase + j) * DIM + c);
    }
  }
}

// ---------------- fused MLP: x=relu((P0+P1)Wg+bg); h=relu(xW1+b1);
//                  u=hW2+b2; un=u/max(||u||,1e-8)  (per 64-row block) --------
__global__ __launch_bounds__(512) void mlp_fused(const float* __restrict__ P,
                                                 const unsigned short* __restrict__ WgT,
                                                 const float* __restrict__ bg,
                                                 const unsigned short* __restrict__ uW1T,
                                                 const unsigned short* __restrict__ iW1T,
                                                 const float* __restrict__ ub1,
                                                 const float* __restrict__ ib1,
                                                 const unsigned short* __restrict__ uW2T,
                                                 const unsigned short* __restrict__ iW2T,
                                                 const float* __restrict__ ub2,
                                                 const float* __restrict__ ib2,
                                                 unsigned short* __restrict__ un) {
  __shared__ char smem[96 * 1024];
  char* const Xa = smem;              // activation A [64 rows][512 B] bf16, 32 KB
  char* const Xb = smem + 32 * 1024;  // activation B [64][512 B], 32 KB
  char* const Bb = smem + 64 * 1024;  // weight stage [256][64] bf16, 32 KB
  __shared__ float rs[64][4];

  const int tid = threadIdx.x, l = tid & 63, w = tid >> 6;
  const int wm = w >> 2, wn = w & 3;  // wave tile 32x64
  const int m0 = blockIdx.x * 64;
  const unsigned short* W1 = (m0 < NUSER) ? uW1T : iW1T;
  const float* b1 = (m0 < NUSER) ? ub1 : ib1;
  const unsigned short* W2 = (m0 < NUSER) ? uW2T : iW2T;
  const float* b2 = (m0 < NUSER) ? ub2 : ib2;
  const int arow = tid >> 4, ac4 = tid & 15;
  const int bn = tid >> 3, bg_ = tid & 7;
  const int lr = l & 15, lk = l >> 4;

  // stage phase-1 input: rows m0..m0+63 of (P0+P1) -> Xa (bf16, swizzled)
#pragma unroll
  for (int step = 0; step < 4; step++)
#pragma unroll
    for (int i = 0; i < 2; i++) {
      int r = i * 32 + arow;
      size_t gi = (size_t)(m0 + r) * DIM + step * 64 + ac4 * 4;
      f32x4 v = *(const f32x4*)(P + gi);
      v += *(const f32x4*)(P + (size_t)NTOT * DIM + gi);
      unsigned lo = pack2bf(v.x, v.y);
      unsigned hi = pack2bf(v.z, v.w);
      int off = r * 512 + ((step * 128 + ac4 * 8) ^ ((r & 7) << 4));
      *(unsigned long long*)(Xa + off) =
          (unsigned long long)lo | ((unsigned long long)hi << 32);
    }

  f32x4 zero = {0.f, 0.f, 0.f, 0.f};
  f32x4 acc[2][4];

  // one GEMM phase: C = A(lds) @ WT^T; returns acc
  auto phase = [&](const char* Alds, const unsigned short* WT) {
#pragma unroll
    for (int i = 0; i < 2; i++)
#pragma unroll
      for (int j = 0; j < 4; j++) acc[i][j] = zero;
    for (int step = 0; step < 4; step++) {
#pragma unroll
      for (int i = 0; i < 4; i++) {
        int n = i * 64 + bn;
        i32x4 v = *(const i32x4*)(WT + (size_t)n * DIM + step * 64 + bg_ * 8);
        int off = (n * 128 + bg_ * 16) ^ ((n & 7) << 4);
        *(i32x4*)(Bb + off) = v;
      }
      __syncthreads();
#pragma unroll
      for (int kh = 0; kh < 2; kh++) {
        s16x8 af[2], bfr[4];
#pragma unroll
        for (int mt = 0; mt < 2; mt++) {
          int r = wm * 32 + mt * 16 + lr;
          int off = r * 512 + ((step * 128 + kh * 64 + lk * 16) ^ ((r & 7) << 4));
          af[mt] = *(const s16x8*)(Alds + off);
        }
#pragma unroll
        for (int nt = 0; nt < 4; nt++) {
          int n = wn * 64 + nt * 16 + lr;
          int off = (n * 128 + kh * 64 + lk * 16) ^ ((n & 7) << 4);
          bfr[nt] = *(const s16x8*)(Bb + off);
        }
#pragma unroll
        for (int mt = 0; mt < 2; mt++)
#pragma unroll
          for (int nt = 0; nt < 4; nt++)
            acc[mt][nt] = __builtin_amdgcn_mfma_f32_16x16x32_bf16(af[mt], bfr[nt],
                                                                  acc[mt][nt], 0, 0, 0);
      }
      __syncthreads();
    }
  };
  // relu(acc+bias) -> activation LDS (bf16, swizzled u16 writes)
  auto reluToLds = [&](const float* bias, char* dst) {
#pragma unroll
    for (int nt = 0; nt < 4; nt++) {
      int c = wn * 64 + nt * 16 + lr;
      float b = bias[c];
#pragma unroll
      for (int mt = 0; mt < 2; mt++) {
        int rbase = wm * 32 + mt * 16 + lk * 4;
#pragma unroll
        for (int j = 0; j < 4; j++) {
          float v = fmaxf(acc[mt][nt][j] + b, 0.f);
          int row = rbase + j;
          int off = row * 512 + ((c * 2) ^ ((row & 7) << 4));
          *(unsigned short*)(dst + off) = f2bf(v);
        }
      }
    }
  };

  __syncthreads();
  // phase 1: x = relu(in @ Wg^T + bg) -> Xb
  phase(Xa, WgT);
  reluToLds(bg, Xb);
  __syncthreads();
  // phase 2: h = relu(x @ W1^T + b1) -> Xa
  phase(Xb, W1);
  reluToLds(b1, Xa);
  __syncthreads();
  // phase 3: u = h @ W2^T + b2; normalize
  phase(Xa, W2);

  float uval[2][4][4];
  float p[2][4];
#pragma unroll
  for (int mt = 0; mt < 2; mt++)
#pragma unroll
    for (int j = 0; j < 4; j++) p[mt][j] = 0.f;
#pragma unroll
  for (int nt = 0; nt < 4; nt++) {
    int c = wn * 64 + nt * 16 + lr;
    float b = b2[c];
#pragma unroll
    for (int mt = 0; mt < 2; mt++)
#pragma unroll
      for (int j = 0; j < 4; j++) {
        float v = acc[mt][nt][j] + b;
        uval[mt][nt][j] = v;
        p[mt][j] += v * v;
      }
  }
#pragma unroll
  for (int d = 1; d < 16; d <<= 1)
#pragma unroll
    for (int mt = 0; mt < 2; mt++)
#pragma unroll
      for (int j = 0; j < 4; j++) p[mt][j] += __shfl_xor(p[mt][j], d, 64);
  if (lr == 0) {
#pragma unroll
    for (int mt = 0; mt < 2; mt++)
#pragma unroll
      for (int j = 0; j < 4; j++) rs[wm * 32 + mt * 16 + lk * 4 + j][wn] = p[mt][j];
  }
  __syncthreads();
#pragma unroll
  for (int mt = 0; mt < 2; mt++) {
    int rl = wm * 32 + mt * 16 + lk * 4;
#pragma unroll
    for (int j = 0; j < 4; j++) {
      float tot = rs[rl + j][0] + rs[rl + j][1] + rs[rl + j][2] + rs[rl + j][3];
      float inv = 1.f / fmaxf(sqrtf(tot), 1e-8f);
#pragma unroll
      for (int nt = 0; nt < 4; nt++) {
        int c = wn * 64 + nt * 16 + lr;
        un[(size_t)(m0 + rl + j) * DIM + c] = f2bf(uval[mt][nt][j] * inv);
      }
    }
  }
}

// ---------------- sim = clip(un @ itn^T) (r6-exact) ----------------
__global__ __launch_bounds__(512) void simk(const unsigned short* __restrict__ UN,
                                            float* __restrict__ out) {
  __shared__ char smem[128 * 1024];
  char* Ab = smem;              // [128][256] bf16 64KB
  char* Bb = smem + 64 * 1024;  // [128][256] bf16 64KB
  const int tid = threadIdx.x, l = tid & 63, w = tid >> 6;
  const int wm = w >> 2, wn = w & 3;  // wave tile 64x32
  const int lin = blockIdx.x + (blockIdx.y << 6);
  const int xcd = lin & 7, slot = lin >> 3;
  const int nblk = xcd * 8 + (slot & 7);
  const int mblk = slot >> 3;
  const int m0 = mblk * 128, n0 = nblk * 128;
  const int lr = l & 15, lk = l >> 4;
  const int sr = tid >> 5, sg = tid & 31;

#pragma unroll
  for (int i = 0; i < 8; i++) {
    int r = i * 16 + sr;
    i32x4 va = *(const i32x4*)(UN + (size_t)(m0 + r) * DIM + sg * 8);
    i32x4 vb = *(const i32x4*)(UN + (size_t)(NUSER + n0 + r) * DIM + sg * 8);
    int off = (r * 512 + sg * 16) ^ ((r & 7) << 4);
    *(i32x4*)(Ab + off) = va;
    *(i32x4*)(Bb + off) = vb;
  }
  __syncthreads();

  f32x4 zero = {0.f, 0.f, 0.f, 0.f};
  f32x4 acc[4][2];
#pragma unroll
  for (int i = 0; i < 4; i++)
#pragma unroll
    for (int j = 0; j < 2; j++) acc[i][j] = zero;

#pragma unroll
  for (int ks = 0; ks < 8; ks++) {
    s16x8 af[4], bfr[2];
#pragma unroll
    for (int mt = 0; mt < 4; mt++) {
      int r = wm * 64 + mt * 16 + lr;
      int off = (r * 512 + ks * 64 + lk * 16) ^ ((r & 7) << 4);
      af[mt] = *(const s16x8*)(Ab + off);
    }
#pragma unroll
    for (int nt = 0; nt < 2; nt++) {
      int n = wn * 32 + nt * 16 + lr;
      int off = (n * 512 + ks * 64 + lk * 16) ^ ((n & 7) << 4);
      bfr[nt] = *(const s16x8*)(Bb + off);
    }
#pragma unroll
    for (int mt = 0; mt < 4; mt++)
#pragma unroll
      for (int nt = 0; nt < 2; nt++)
        acc[mt][nt] = __builtin_amdgcn_mfma_f32_16x16x32_bf16(af[mt], bfr[nt],
                                                              acc[mt][nt], 0, 0, 0);
  }

#pragma unroll
  for (int mt = 0; mt < 4; mt++) {
    int rbase = m0 + wm * 64 + mt * 16 + lk * 4;
#pragma unroll
    for (int nt = 0; nt < 2; nt++) {
      int c = n0 + wn * 32 + nt * 16 + lr;
#pragma unroll
      for (int j = 0; j < 4; j++) {
        float v = fminf(fmaxf(acc[mt][nt][j], 1e-6f), 1.0f);
        __builtin_nontemporal_store(v, out + (size_t)(rbase + j) * 8192 + c);
      }
    }
  }
}

extern "C" void kernel_launch(void* const* d_in, const int* in_sizes, int n_in,
                              void* d_out, int out_size, void* d_ws, size_t ws_size,
                              hipStream_t stream) {
  const float* A    = (const float*)d_in[0];
  const float* feat = (const float*)d_in[1];
  const float* Wg   = (const float*)d_in[2];
  const float* bg   = (const float*)d_in[3];
  const float* uW1  = (const float*)d_in[4];
  const float* ub1  = (const float*)d_in[5];
  const float* uW2  = (const float*)d_in[6];
  const float* ub2  = (const float*)d_in[7];
  const float* iW1  = (const float*)d_in[8];
  const float* ib1  = (const float*)d_in[9];
  const float* iW2  = (const float*)d_in[10];
  const float* ib2  = (const float*)d_in[11];
  float* out = (float*)d_out;
  char* ob = (char*)d_out;

  // transient scratch inside d_out (dead before simk overwrites everything)
  float*          F1p  = (float*)(ob + 0);                 // 32 MiB: [2][16384][256] f32
  unsigned short* Ft   = (unsigned short*)(ob + 33554432); // 8 MiB: [256][16384] bf16
  unsigned short* WT5  = (unsigned short*)(ob + 41943040); // 5 x 128 KiB
  unsigned short* WgT  = WT5;
  unsigned short* uW1T = WT5 + 1 * 65536;
  unsigned short* uW2T = WT5 + 2 * 65536;
  unsigned short* iW1T = WT5 + 3 * 65536;
  unsigned short* iW2T = WT5 + 4 * 65536;
  unsigned short* UN   = (unsigned short*)d_ws;            // 8 MiB, survives into simk

  transpose_cvt<<<dim3(256, 4), 256, 0, stream>>>(feat, Ft, NTOT, DIM);
  transpose_w5<<<dim3(4, 4, 5), 256, 0, stream>>>(Wg, uW1, uW2, iW1, iW2, WT5);

  gemm1<<<dim3(256), 512, 0, stream>>>(A, Ft, F1p);
  mlp_fused<<<dim3(256), 512, 0, stream>>>(F1p, WgT, bg, uW1T, iW1T, ub1, ib1,
                                           uW2T, iW2T, ub2, ib2, UN);
  simk<<<dim3(64, 64), 512, 0, stream>>>(UN, out);
}